// Round 8
// baseline (842.478 us; speedup 1.0000x reference)
//
#include <hip/hip_runtime.h>

#define NPTS 4096
#define QN   16384
#define KNN  24

// ---- workspace offsets (float units) ----
static constexpr size_t OFF_EDGES = 0;                         // int[QN*24]
static constexpr size_t OFF_BIG   = 393216;
static constexpr size_t OFF_A     = OFF_BIG;                   // float[QN*128]
static constexpr size_t OFF_C     = OFF_BIG + 2097152;         // float[QN*128]
static constexpr size_t OFF_M     = OFF_BIG + 4194304;         // float[QN*128]
static constexpr size_t OFF_L0    = OFF_BIG + 6553600;         // float[QN*64]
static constexpr size_t OFF_L1    = OFF_L0 + 1048576;          // float[QN*128]
static constexpr size_t ST_BASE   = OFF_L1 + 2097152;
static constexpr size_t ST_BN1    = ST_BASE;                   // 256
static constexpr size_t ST_GM     = ST_BASE + 256;             // 256
static constexpr size_t ST_L0     = ST_BASE + 512;             // 128
static constexpr size_t ST_L1     = ST_BASE + 640;             // 256
static constexpr size_t ST_L2     = ST_BASE + 896;             // 512
static constexpr size_t RMX_GM    = ST_BASE + 1408;            // 512 uint
static constexpr size_t RMN_GM    = ST_BASE + 1920;            // 512 uint
static constexpr size_t RMX_L2    = ST_BASE + 2432;            // 1024 uint
static constexpr size_t RMN_L2    = ST_BASE + 3456;            // 1024 uint
static constexpr int    ST_COUNT  = 4480;
static constexpr size_t OFF_CTRL  = ST_BASE + 4480;            // 2 uint (barrier cnt, gen)

__device__ inline unsigned fmap(float f) {
    unsigned u = __float_as_uint(f);
    return (u & 0x80000000u) ? ~u : (u | 0x80000000u);
}
__device__ inline float funmap(unsigned u) {
    unsigned v = (u & 0x80000000u) ? (u & 0x7fffffffu) : ~u;
    return __uint_as_float(v);
}

// XCD-affinity decode: batch b owns XCD pair {2b,2b+1} (XCD = bid%8 heuristic)
__device__ inline void xcd_decode(int v, int& b, int& t) {
    b = (v & 7) >> 1;
    t = ((v >> 3) << 1) | (v & 1);
}

// Hand-rolled grid barrier: leader-only arrival + generation spin w/ s_sleep.
// cnt reset happens-before gen release-bump -> safe across reuse.
__device__ inline void gbar(unsigned* cnt, unsigned* gen, unsigned nb) {
    __syncthreads();
    if (threadIdx.x == 0) {
        __threadfence();
        unsigned g = __hip_atomic_load(gen, __ATOMIC_RELAXED, __HIP_MEMORY_SCOPE_AGENT);
        unsigned old = __hip_atomic_fetch_add(cnt, 1u, __ATOMIC_ACQ_REL, __HIP_MEMORY_SCOPE_AGENT);
        if (old == nb - 1u) {
            __hip_atomic_store(cnt, 0u, __ATOMIC_RELAXED, __HIP_MEMORY_SCOPE_AGENT);
            __hip_atomic_fetch_add(gen, 1u, __ATOMIC_RELEASE, __HIP_MEMORY_SCOPE_AGENT);
        } else {
            while (__hip_atomic_load(gen, __ATOMIC_ACQUIRE, __HIP_MEMORY_SCOPE_AGENT) == g)
                __builtin_amdgcn_s_sleep(16);
        }
        __threadfence();
    }
    __syncthreads();
}

// ============================================================
// Kernel A: knn (4096) | feat (2048) | L0 layer (256) | init (1)
// ============================================================
__global__ __launch_bounds__(256) void kA(const float* __restrict__ xyz,
                                          const float* __restrict__ pts,
                                          const float* __restrict__ ec_w,
                                          const float* __restrict__ w0,
                                          const float* __restrict__ bias0,
                                          int* __restrict__ edges,
                                          float* __restrict__ afeat,
                                          float* __restrict__ cfeat,
                                          float* __restrict__ l0raw,
                                          float* __restrict__ stL0,
                                          unsigned* __restrict__ stz) {
    __shared__ __align__(16) unsigned char smem[25856];
    int u = blockIdx.x;
    int tid = threadIdx.x;
    if (u < 4096) {
        // ---- wave-cooperative exact KNN (ballot-compaction, unchanged) ----
        float4* cand = (float4*)smem;
        unsigned long long* bufall = (unsigned long long*)(smem + 16384);
        int b = u >> 10;
        int wave = tid >> 6, lane = tid & 63;
        int n = ((u & 1023) << 2) + wave;
        const float* xb = xyz + (size_t)b * 3 * 4096;
        unsigned long long* wbuf = bufall + wave * 128;

        float xq = xb[n], yq = xb[4096 + n], zq = xb[8192 + n];
        float sqq = __fadd_rn(__fadd_rn(__fmul_rn(xq, xq), __fmul_rn(yq, yq)), __fmul_rn(zq, zq));

        unsigned T = 0xFFFFFFFFu;
        int count = 0;

        auto reduce = [&]() {
            unsigned long long ka = (lane < count) ? wbuf[lane] : ~0ull;
            int ra = 0;
            if (count > 64) {
                unsigned long long kb = (lane + 64 < count) ? wbuf[lane + 64] : ~0ull;
                int rb = 0;
                for (int j = 0; j < count; ++j) {
                    unsigned long long kj = wbuf[j];
                    ra += (kj < ka);
                    rb += (kj < kb);
                }
                if (rb < 25) wbuf[rb] = kb;
            } else {
                for (int j = 0; j < count; ++j) {
                    unsigned long long kj = wbuf[j];
                    ra += (kj < ka);
                }
            }
            if (ra < 25) wbuf[ra] = ka;
            count = 25;
            T = (unsigned)(wbuf[24] >> 32);
        };

        for (int strip = 0; strip < 4; ++strip) {
            __syncthreads();
            for (int i = tid; i < 1024; i += 256) {
                int j = strip * 1024 + i;
                float x = xb[j], y = xb[4096 + j], z = xb[8192 + j];
                float sq = __fadd_rn(__fadd_rn(__fmul_rn(x, x), __fmul_rn(y, y)), __fmul_rn(z, z));
                cand[i] = make_float4(x, y, z, sq);
            }
            __syncthreads();
            for (int t = 0; t < 16; ++t) {
                float4 cv = cand[t * 64 + lane];
                float dot = __fadd_rn(__fadd_rn(__fmul_rn(xq, cv.x), __fmul_rn(yq, cv.y)), __fmul_rn(zq, cv.z));
                float d = __fsub_rn(__fadd_rn(sqq, cv.w), __fmul_rn(2.0f, dot));
                unsigned du = fmap(d);
                bool surv = (du <= T);
                unsigned long long m = __ballot(surv);
                if (m) {
                    if (surv) {
                        int ofs = __popcll(m & ((1ull << lane) - 1ull));
                        unsigned idx = (unsigned)(strip * 1024 + t * 64 + lane);
                        wbuf[count + ofs] = ((unsigned long long)du << 32) | idx;
                    }
                    count += (int)__popcll(m);
                    if (count >= 64) reduce();
                }
            }
        }
        reduce();
        if (lane >= 1 && lane < 25)
            edges[((size_t)(b * 4096 + n)) * KNN + lane - 1] = (int)(unsigned)(wbuf[lane] & 0xFFFFFFFFull);
    } else if (u < 6144) {
        // ---- feat: one 64x32 GEMM slice (a or c) per block ----
        int v = u - 4096;
        int b, t;
        xcd_decode(v, b, t);
        int nchunk = t & 63, sub = t >> 6;
        int which = sub >> 2;
        int o0 = (sub & 3) * 32;
        int n0 = nchunk * 64;

        float* inl = (float*)smem;            // 64*65
        float* wl  = (float*)(smem + 16640);  // 64*36
        const float* pb = pts + (size_t)b * 64 * 4096;

        for (int idx = tid; idx < 64 * 64; idx += 256) {
            int c = idx >> 6, p = idx & 63;
            inl[p * 65 + c] = pb[(size_t)c * 4096 + n0 + p];
        }
        for (int idx = tid; idx < 64 * 32; idx += 256) {
            int cc = idx & 63, o = idx >> 6;
            float w2v = ec_w[(o0 + o) * 128 + 64 + cc];
            wl[cc * 36 + o] = which ? w2v : (ec_w[(o0 + o) * 128 + cc] - w2v);
        }
        __syncthreads();

        int ng = tid & 15, og = tid >> 4;
        float acc[4][2] = {{0.f, 0.f}, {0.f, 0.f}, {0.f, 0.f}, {0.f, 0.f}};
        for (int cc = 0; cc < 64; ++cc) {
            float pv[4];
            #pragma unroll
            for (int r = 0; r < 4; ++r) pv[r] = inl[(ng * 4 + r) * 65 + cc];
            float2 wv = *(const float2*)&wl[cc * 36 + og * 2];
            #pragma unroll
            for (int r = 0; r < 4; ++r) {
                acc[r][0] = fmaf(pv[r], wv.x, acc[r][0]);
                acc[r][1] = fmaf(pv[r], wv.y, acc[r][1]);
            }
        }
        __syncthreads();
        #pragma unroll
        for (int r = 0; r < 4; ++r) {
            wl[(ng * 4 + r) * 36 + og * 2 + 0] = acc[r][0];
            wl[(ng * 4 + r) * 36 + og * 2 + 1] = acc[r][1];
        }
        __syncthreads();
        float* dst = (which ? cfeat : afeat) + ((size_t)(b * 4096 + n0)) * 128 + o0;
        for (int idx = tid; idx < 64 * 32; idx += 256) {
            int p = idx >> 5, o = idx & 31;
            dst[(size_t)p * 128 + o] = wl[p * 36 + o];
        }
    } else if (u < 6400) {
        // ---- L0: concat(xyz,pts)[67] -> 64 outs, 64-pt chunk ----
        int v = u - 6144;
        int b, chunk;
        xcd_decode(v, b, chunk);              // chunk in [0,64)
        int n0 = chunk * 64;
        int q0 = b * 4096 + n0;
        float* inl = (float*)smem;            // [32][68]
        float* wl  = (float*)(smem + 8704);   // [32][68]
        int ng = tid & 15, og = tid >> 4;
        float acc[4][4] = {};

        for (int ct = 0; ct < 67; ct += 32) {
            int CT = (67 - ct < 32) ? (67 - ct) : 32;
            __syncthreads();
            for (int idx = tid; idx < CT * 16; idx += 256) {
                int p4 = idx & 15, c = idx >> 4;
                int ch = ct + c;
                const float* srow = (ch < 3) ? &xyz[((size_t)(b * 3 + ch) << 12) + n0]
                                             : &pts[((size_t)(b * 64 + ch - 3) << 12) + n0];
                float4 v4;
                v4.x = srow[p4 * 4 + 0];
                v4.y = srow[p4 * 4 + 1];
                v4.z = srow[p4 * 4 + 2];
                v4.w = srow[p4 * 4 + 3];
                *(float4*)&inl[c * 68 + p4 * 4] = v4;
            }
            for (int idx = tid; idx < CT * 64; idx += 256) {
                int o = idx & 63, cc = idx >> 6;
                wl[cc * 68 + o] = w0[o * 67 + ct + cc];
            }
            __syncthreads();
            for (int cc = 0; cc < CT; ++cc) {
                float4 pv = *(const float4*)&inl[cc * 68 + ng * 4];
                float4 wv = *(const float4*)&wl[cc * 68 + og * 4];
                float pvv[4] = {pv.x, pv.y, pv.z, pv.w};
                float wvv[4] = {wv.x, wv.y, wv.z, wv.w};
                #pragma unroll
                for (int r = 0; r < 4; ++r)
                    #pragma unroll
                    for (int k = 0; k < 4; ++k)
                        acc[r][k] = fmaf(pvv[r], wvv[k], acc[r][k]);
            }
        }
        #pragma unroll
        for (int k = 0; k < 4; ++k) {
            float bv = bias0[og * 4 + k];
            #pragma unroll
            for (int r = 0; r < 4; ++r) acc[r][k] += bv;
        }
        __syncthreads();
        float* st = inl;  // [64][68]
        #pragma unroll
        for (int r = 0; r < 4; ++r)
            #pragma unroll
            for (int k = 0; k < 4; ++k)
                st[(ng * 4 + r) * 68 + og * 4 + k] = acc[r][k];
        __syncthreads();
        for (int idx = tid; idx < 1024; idx += 256) {
            int p = idx >> 4, o4 = (idx & 15) * 4;
            *(float4*)&l0raw[(size_t)(q0 + p) * 64 + o4] = *(const float4*)&st[p * 68 + o4];
        }
        if (tid < 64) {
            float s1 = 0.f, s2 = 0.f;
            #pragma unroll 8
            for (int p = 0; p < 64; ++p) {
                float vv = st[p * 68 + tid];
                s1 += vv;
                s2 = fmaf(vv, vv, s2);
            }
            atomicAdd(&stL0[tid], s1);
            atomicAdd(&stL0[64 + tid], s2);
        }
    } else {
        // init stats/extremes (skip ST_L0 range [512,640): memset'd + L0 races)
        for (int i = tid; i < ST_COUNT; i += 256) {
            if (i >= 512 && i < 640) continue;
            bool sentinel = (i >= (int)(RMN_GM - ST_BASE) && i < (int)(RMX_L2 - ST_BASE)) ||
                            (i >= (int)(RMN_L2 - ST_BASE));
            stz[i] = sentinel ? 0xFFFFFFFFu : 0u;
        }
    }
}

// ============================================================
// 128-pt x 128-out dense layer, 8x8 thread tiles, k-tile 32.
// MODE: 1 = relu(bn(in)), 2 = leaky(bn(in)).
// ============================================================
template<int I, int TO, int MODE, bool RAW, bool MINMAX>
__device__ void layer128(unsigned char* smem, int b, int chunk, int o0,
    const float* __restrict__ inraw, const float* __restrict__ inst, float rcnt,
    const float* __restrict__ ing, const float* __restrict__ inbe,
    const float* __restrict__ W, const float* __restrict__ bias,
    float* __restrict__ outraw, float* __restrict__ outst,
    unsigned* __restrict__ rmax, unsigned* __restrict__ rmin)
{
    float* ns  = (float*)smem;                     // 128
    float* nb  = ns + 128;                         // 128
    float* inl = (float*)(smem + 1024);            // [32][132]
    float* wl  = (float*)(smem + 1024 + 16896);    // [32][132]
    int tid = threadIdx.x;
    int ng = tid & 15, og = tid >> 4;
    int q0 = b * 4096 + chunk * 128;

    if (tid < I) {
        float m = inst[tid] * rcnt;
        float v = inst[I + tid] * rcnt - m * m;
        float sc = ing[tid] / sqrtf(v + 1e-5f);
        ns[tid] = sc;
        nb[tid] = inbe[tid] - m * sc;
    }

    float acc[8][8] = {};
    for (int ct = 0; ct < I; ct += 32) {
        __syncthreads();  // ns ready (iter 0) / prev tile consumed
        const float* src = inraw + (size_t)q0 * I + ct;
        #pragma unroll
        for (int it = 0; it < 4; ++it) {
            int idx = tid + it * 256;
            int c = idx & 31, p4 = idx >> 5;
            float sc_ = ns[ct + c], sh_ = nb[ct + c];
            float4 v;
            v.x = fmaf(src[(size_t)(p4 * 4 + 0) * I + c], sc_, sh_);
            v.y = fmaf(src[(size_t)(p4 * 4 + 1) * I + c], sc_, sh_);
            v.z = fmaf(src[(size_t)(p4 * 4 + 2) * I + c], sc_, sh_);
            v.w = fmaf(src[(size_t)(p4 * 4 + 3) * I + c], sc_, sh_);
            if (MODE == 1) {
                v.x = fmaxf(v.x, 0.f); v.y = fmaxf(v.y, 0.f);
                v.z = fmaxf(v.z, 0.f); v.w = fmaxf(v.w, 0.f);
            } else {
                v.x = (v.x > 0.f) ? v.x : 0.2f * v.x;
                v.y = (v.y > 0.f) ? v.y : 0.2f * v.y;
                v.z = (v.z > 0.f) ? v.z : 0.2f * v.z;
                v.w = (v.w > 0.f) ? v.w : 0.2f * v.w;
            }
            *(float4*)&inl[c * 132 + p4 * 4] = v;
        }
        #pragma unroll
        for (int it = 0; it < 4; ++it) {
            int idx = tid + it * 256;
            int o = idx & 127, c4 = idx >> 7;
            float4 w4 = *(const float4*)&W[(size_t)(o0 + o) * I + ct + c4 * 4];
            wl[(c4 * 4 + 0) * 132 + o] = w4.x;
            wl[(c4 * 4 + 1) * 132 + o] = w4.y;
            wl[(c4 * 4 + 2) * 132 + o] = w4.z;
            wl[(c4 * 4 + 3) * 132 + o] = w4.w;
        }
        __syncthreads();
        for (int cc = 0; cc < 32; ++cc) {
            float4 pl = *(const float4*)&inl[cc * 132 + ng * 4];
            float4 ph = *(const float4*)&inl[cc * 132 + 64 + ng * 4];
            float4 wo = *(const float4*)&wl[cc * 132 + og * 4];
            float4 wh = *(const float4*)&wl[cc * 132 + 64 + og * 4];
            float pv[8] = {pl.x, pl.y, pl.z, pl.w, ph.x, ph.y, ph.z, ph.w};
            float wv[8] = {wo.x, wo.y, wo.z, wo.w, wh.x, wh.y, wh.z, wh.w};
            #pragma unroll
            for (int r = 0; r < 8; ++r)
                #pragma unroll
                for (int k = 0; k < 8; ++k)
                    acc[r][k] = fmaf(pv[r], wv[k], acc[r][k]);
        }
    }

    if (bias != nullptr) {
        #pragma unroll
        for (int k = 0; k < 8; ++k) {
            int o = (k < 4) ? (og * 4 + k) : (64 + og * 4 + k - 4);
            float bv = bias[o0 + o];
            #pragma unroll
            for (int r = 0; r < 8; ++r) acc[r][k] += bv;
        }
    }

    if (RAW) {
        float* st = (float*)(smem + 1024);   // [128][68]
        #pragma unroll
        for (int h = 0; h < 2; ++h) {
            __syncthreads();
            #pragma unroll
            for (int r = 0; r < 8; ++r) {
                int p = (r < 4) ? (ng * 4 + r) : (64 + ng * 4 + r - 4);
                #pragma unroll
                for (int k = 0; k < 4; ++k)
                    st[p * 68 + og * 4 + k] = acc[r][h * 4 + k];
            }
            __syncthreads();
            for (int idx = tid; idx < 2048; idx += 256) {
                int p = idx >> 4, o4 = (idx & 15) * 4;
                *(float4*)&outraw[(size_t)(q0 + p) * TO + h * 64 + o4] = *(const float4*)&st[p * 68 + o4];
            }
            if (tid < 64) {
                float s1 = 0.f, s2 = 0.f;
                #pragma unroll 8
                for (int p = 0; p < 128; ++p) {
                    float vv = st[p * 68 + tid];
                    s1 += vv;
                    s2 = fmaf(vv, vv, s2);
                }
                atomicAdd(&outst[h * 64 + tid], s1);
                atomicAdd(&outst[TO + h * 64 + tid], s2);
            }
        }
    } else {
        float* red = (float*)(smem + 1024);  // [128*17] float4-slots
        __syncthreads();
        #pragma unroll
        for (int k = 0; k < 8; ++k) {
            int o = (k < 4) ? (og * 4 + k) : (64 + og * 4 + k - 4);
            float s1 = 0.f, s2 = 0.f;
            float mx = -__builtin_inff(), mn = __builtin_inff();
            #pragma unroll
            for (int r = 0; r < 8; ++r) {
                float vv = acc[r][k];
                s1 += vv;
                s2 = fmaf(vv, vv, s2);
                mx = fmaxf(mx, vv);
                mn = fminf(mn, vv);
            }
            *(float4*)&red[(o * 17 + ng) * 4] = make_float4(s1, s2, mx, mn);
        }
        __syncthreads();
        if (tid < 128) {
            float s1 = 0.f, s2 = 0.f;
            float mx = -__builtin_inff(), mn = __builtin_inff();
            #pragma unroll
            for (int g2 = 0; g2 < 16; ++g2) {
                float4 t4 = *(const float4*)&red[(tid * 17 + g2) * 4];
                s1 += t4.x;
                s2 += t4.y;
                mx = fmaxf(mx, t4.z);
                mn = fminf(mn, t4.w);
            }
            atomicAdd(&outst[o0 + tid], s1);
            atomicAdd(&outst[TO + o0 + tid], s2);
            if (MINMAX) {
                atomicMax(&rmax[b * TO + o0 + tid], fmap(mx));
                atomicMin(&rmin[b * TO + o0 + tid], fmap(mn));
            }
        }
    }
}

// ============================================================
// Fused kernel: gather -> (GM | L1) -> L2 -> head
// (cooperative launch for co-residency; custom gbar barriers)
// ============================================================
struct P2 {
    const float* afeat; const float* cfeat; const int* edges;
    float* M; float* stBN1;
    const float* ec_g; const float* ec_b; const float* gm_w;
    float* stGM; unsigned* rmxGM; unsigned* rmnGM;
    const float* l0raw; const float* stL0; const float* g0; const float* be0;
    const float* w1; const float* bias1; float* l1raw; float* stL1;
    const float* g1; const float* be1; const float* w2; const float* bias2;
    float* stL2; unsigned* rmxL2; unsigned* rmnL2;
    const float* gm_g; const float* gm_b; const float* g2; const float* be2;
    const float* fu_w; const float* fu_g; const float* fu_b; float* out;
    unsigned* bcnt; unsigned* bgen;
};

__global__ __launch_bounds__(256, 4) void kFused(P2 p) {
    __shared__ __align__(16) unsigned char smem[36864];
    int bid = blockIdx.x;
    int gsz = gridDim.x;
    int tid = threadIdx.x;

    // ---------------- Phase B: neighbor gather + BN1 stats ----------------
    for (int u = bid; u < 1024; u += gsz) {
        int* eL = (int*)smem;                       // 16*24
        float* red = (float*)(smem + 1536);         // 8*132
        int b, chunk;
        xcd_decode(u, b, chunk);                    // chunk in [0,256)
        int q0 = b * 4096 + chunk * 16;
        __syncthreads();
        for (int idx = tid; idx < 16 * KNN; idx += 256) eL[idx] = p.edges[(size_t)q0 * KNN + idx];
        __syncthreads();

        int m = tid & 31;
        int g = tid >> 5;
        int bbase = b << 12;
        float s1[4] = {0.f, 0.f, 0.f, 0.f}, s2[4] = {0.f, 0.f, 0.f, 0.f};

        #pragma unroll
        for (int half = 0; half < 2; ++half) {
            int pp = g + half * 8;
            int q = q0 + pp;
            float mx0 = -__builtin_inff(), mx1 = mx0, mx2 = mx0, mx3 = mx0;
            float sv0 = 0.f, sv1 = 0.f, sv2 = 0.f, sv3 = 0.f;
            float qv0 = 0.f, qv1 = 0.f, qv2 = 0.f, qv3 = 0.f;
            #pragma unroll 8
            for (int k = 0; k < KNN; ++k) {
                int e = eL[pp * KNN + k];
                float4 v = *(const float4*)&p.cfeat[((size_t)(bbase + e) << 7) + m * 4];
                mx0 = fmaxf(mx0, v.x); sv0 += v.x; qv0 = fmaf(v.x, v.x, qv0);
                mx1 = fmaxf(mx1, v.y); sv1 += v.y; qv1 = fmaf(v.y, v.y, qv1);
                mx2 = fmaxf(mx2, v.z); sv2 += v.z; qv2 = fmaf(v.z, v.z, qv2);
                mx3 = fmaxf(mx3, v.w); sv3 += v.w; qv3 = fmaf(v.w, v.w, qv3);
            }
            float4 a = *(const float4*)&p.afeat[((size_t)q << 7) + m * 4];
            float4 mo = make_float4(a.x + mx0, a.y + mx1, a.z + mx2, a.w + mx3);
            *(float4*)&p.M[((size_t)q << 7) + m * 4] = mo;
            s1[0] += fmaf(24.f, a.x, sv0); s2[0] += 24.f * a.x * a.x + 2.f * a.x * sv0 + qv0;
            s1[1] += fmaf(24.f, a.y, sv1); s2[1] += 24.f * a.y * a.y + 2.f * a.y * sv1 + qv1;
            s1[2] += fmaf(24.f, a.z, sv2); s2[2] += 24.f * a.z * a.z + 2.f * a.z * sv2 + qv2;
            s1[3] += fmaf(24.f, a.w, sv3); s2[3] += 24.f * a.w * a.w + 2.f * a.w * sv3 + qv3;
        }
        #pragma unroll
        for (int j = 0; j < 4; ++j) red[g * 132 + m * 4 + j] = s1[j];
        __syncthreads();
        if (tid < 128) {
            float t = 0.f;
            #pragma unroll
            for (int gg = 0; gg < 8; ++gg) t += red[gg * 132 + tid];
            atomicAdd(&p.stBN1[tid], t);
        }
        __syncthreads();
        #pragma unroll
        for (int j = 0; j < 4; ++j) red[g * 132 + m * 4 + j] = s2[j];
        __syncthreads();
        if (tid < 128) {
            float t = 0.f;
            #pragma unroll
            for (int gg = 0; gg < 8; ++gg) t += red[gg * 132 + tid];
            atomicAdd(&p.stBN1[128 + tid], t);
        }
    }
    gbar(p.bcnt, p.bgen, gridDim.x);

    // ---------------- Phase C: GM (128 jobs) | L1 (128 jobs) ----------------
    for (int u = bid; u < 256; u += gsz) {
        if (u < 128) {
            int b, chunk;
            xcd_decode(u, b, chunk);   // chunk in [0,32)
            layer128<128, 128, 2, false, true>(smem, b, chunk, 0,
                p.M, p.stBN1, 1.0f / 393216.0f, p.ec_g, p.ec_b,
                p.gm_w, nullptr, nullptr, p.stGM, p.rmxGM, p.rmnGM);
        } else {
            int b, chunk;
            xcd_decode(u - 128, b, chunk);
            layer128<64, 128, 1, true, false>(smem, b, chunk, 0,
                p.l0raw, p.stL0, 1.0f / 16384.0f, p.g0, p.be0,
                p.w1, p.bias1, p.l1raw, p.stL1, nullptr, nullptr);
        }
    }
    gbar(p.bcnt, p.bgen, gridDim.x);

    // ---------------- Phase D: L2 (256 jobs = 128-pt x 128-out halves) ----------------
    for (int u = bid; u < 256; u += gsz) {
        int half = u >> 7;
        int b, chunk;
        xcd_decode(u & 127, b, chunk);  // chunk in [0,32)
        layer128<128, 256, 1, false, true>(smem, b, chunk, half * 128,
            p.l1raw, p.stL1, 1.0f / 16384.0f, p.g1, p.be1,
            p.w2, p.bias2, nullptr, p.stL2, p.rmxL2, p.rmnL2);
    }
    gbar(p.bcnt, p.bgen, gridDim.x);

    // ---------------- Phase E: final head (block 0) ----------------
    if (bid == 0) {
        float* fl = (float*)smem;   // 4*384
        const float rc = 1.0f / 16384.0f;
        {   // point branch (relu), O=256
            int o = tid;
            float m = p.stL2[o] * rc;
            float v = p.stL2[256 + o] * rc - m * m;
            float sc = p.g2[o] / sqrtf(v + 1e-5f);
            float sh = p.be2[o] - m * sc;
            #pragma unroll
            for (int b = 0; b < 4; ++b) {
                float f1 = fmaxf(fmaf(funmap(p.rmxL2[b * 256 + o]), sc, sh), 0.f);
                float f2 = fmaxf(fmaf(funmap(p.rmnL2[b * 256 + o]), sc, sh), 0.f);
                fl[b * 384 + o] = fmaxf(f1, f2);
            }
        }
        if (tid < 128) {   // graph branch (leaky), O=128
            int o = tid;
            float m = p.stGM[o] * rc;
            float v = p.stGM[128 + o] * rc - m * m;
            float sc = p.gm_g[o] / sqrtf(v + 1e-5f);
            float sh = p.gm_b[o] - m * sc;
            #pragma unroll
            for (int b = 0; b < 4; ++b) {
                float x1 = fmaf(funmap(p.rmxGM[b * 128 + o]), sc, sh);
                x1 = (x1 > 0.f) ? x1 : 0.2f * x1;
                float x2 = fmaf(funmap(p.rmnGM[b * 128 + o]), sc, sh);
                x2 = (x2 > 0.f) ? x2 : 0.2f * x2;
                fl[b * 384 + 256 + o] = fmaxf(x1, x2);
            }
        }
        __syncthreads();
        int o = tid;
        float f[4];
        #pragma unroll
        for (int bb = 0; bb < 4; ++bb) {
            float acc = 0.f;
            for (int c = 0; c < 384; ++c) acc = fmaf(fl[bb * 384 + c], p.fu_w[(size_t)o * 384 + c], acc);
            f[bb] = acc;
        }
        float m = 0.25f * (f[0] + f[1] + f[2] + f[3]);
        float var = 0.f;
        #pragma unroll
        for (int bb = 0; bb < 4; ++bb) { float tt = f[bb] - m; var = fmaf(tt, tt, var); }
        var *= 0.25f;
        float inv = 1.0f / sqrtf(var + 1e-5f);
        float gv = p.fu_g[o], bv = p.fu_b[o];
        #pragma unroll
        for (int bb = 0; bb < 4; ++bb) {
            float xx = (f[bb] - m) * inv * gv + bv;
            xx = (xx > 0.0f) ? xx : 0.2f * xx;
            p.out[bb * 256 + o] = xx;
        }
    }
}

extern "C" void kernel_launch(void* const* d_in, const int* in_sizes, int n_in,
                              void* d_out, int out_size, void* d_ws, size_t ws_size,
                              hipStream_t stream) {
    const float* xyz   = (const float*)d_in[0];
    const float* pts   = (const float*)d_in[1];
    const float* ec_w  = (const float*)d_in[2];
    const float* ec_g  = (const float*)d_in[3];
    const float* ec_b  = (const float*)d_in[4];
    const float* gm_w  = (const float*)d_in[5];
    const float* gm_g  = (const float*)d_in[6];
    const float* gm_b  = (const float*)d_in[7];
    const float* w0    = (const float*)d_in[8];
    const float* bias0 = (const float*)d_in[9];
    const float* g0    = (const float*)d_in[10];
    const float* be0   = (const float*)d_in[11];
    const float* w1    = (const float*)d_in[12];
    const float* bias1 = (const float*)d_in[13];
    const float* g1    = (const float*)d_in[14];
    const float* be1   = (const float*)d_in[15];
    const float* w2    = (const float*)d_in[16];
    const float* bias2 = (const float*)d_in[17];
    const float* g2    = (const float*)d_in[18];
    const float* be2   = (const float*)d_in[19];
    const float* fu_w  = (const float*)d_in[20];
    const float* fu_g  = (const float*)d_in[21];
    const float* fu_b  = (const float*)d_in[22];

    float* ws = (float*)d_ws;
    float* out = (float*)d_out;

    // stL0 + barrier control must be zero before use (ws is re-poisoned)
    hipMemsetAsync(ws + ST_L0, 0, 128 * sizeof(float), stream);
    hipMemsetAsync(ws + OFF_CTRL, 0, 2 * sizeof(unsigned), stream);

    kA<<<6401, 256, 0, stream>>>(xyz, pts, ec_w, w0, bias0,
                                 (int*)(ws + OFF_EDGES), ws + OFF_A, ws + OFF_C,
                                 ws + OFF_L0, ws + ST_L0, (unsigned*)(ws + ST_BASE));

    P2 p2;
    p2.afeat = ws + OFF_A;  p2.cfeat = ws + OFF_C;  p2.edges = (const int*)(ws + OFF_EDGES);
    p2.M = ws + OFF_M;      p2.stBN1 = ws + ST_BN1;
    p2.ec_g = ec_g;         p2.ec_b = ec_b;          p2.gm_w = gm_w;
    p2.stGM = ws + ST_GM;   p2.rmxGM = (unsigned*)(ws + RMX_GM); p2.rmnGM = (unsigned*)(ws + RMN_GM);
    p2.l0raw = ws + OFF_L0; p2.stL0 = ws + ST_L0;    p2.g0 = g0;  p2.be0 = be0;
    p2.w1 = w1;             p2.bias1 = bias1;        p2.l1raw = ws + OFF_L1; p2.stL1 = ws + ST_L1;
    p2.g1 = g1;             p2.be1 = be1;            p2.w2 = w2;  p2.bias2 = bias2;
    p2.stL2 = ws + ST_L2;   p2.rmxL2 = (unsigned*)(ws + RMX_L2); p2.rmnL2 = (unsigned*)(ws + RMN_L2);
    p2.gm_g = gm_g;         p2.gm_b = gm_b;          p2.g2 = g2;  p2.be2 = be2;
    p2.fu_w = fu_w;         p2.fu_g = fu_g;          p2.fu_b = fu_b; p2.out = out;
    p2.bcnt = (unsigned*)(ws + OFF_CTRL);
    p2.bgen = (unsigned*)(ws + OFF_CTRL) + 1;

    void* args[] = {&p2};
    int maxB = 0;
    hipOccupancyMaxActiveBlocksPerMultiprocessor(&maxB, (const void*)kFused, 256, 0);
    if (maxB < 1) maxB = 1;
    int grid = maxB * 256;
    if (grid > 1024) grid = 1024;
    hipLaunchCooperativeKernel((const void*)kFused, dim3(grid), dim3(256), args, 0, stream);
}

// Round 9
// 346.112 us; speedup vs baseline: 2.4341x; 2.4341x over previous
//
#include <hip/hip_runtime.h>

#define NPTS 4096
#define QN   16384
#define KNN  24

// ---- workspace offsets (float units) ----
static constexpr size_t OFF_EDGES = 0;                         // int[QN*24]
static constexpr size_t OFF_BIG   = 393216;
static constexpr size_t OFF_A     = OFF_BIG;                   // float[QN*128]
static constexpr size_t OFF_C     = OFF_BIG + 2097152;         // float[QN*128]
static constexpr size_t OFF_M     = OFF_BIG + 4194304;         // float[QN*128]
static constexpr size_t OFF_L0    = OFF_BIG + 6553600;         // float[QN*64]
static constexpr size_t OFF_L1    = OFF_L0 + 1048576;          // float[QN*128]
static constexpr size_t ST_BASE   = OFF_L1 + 2097152;
static constexpr size_t ST_BN1    = ST_BASE;                   // 256
static constexpr size_t ST_GM     = ST_BASE + 256;             // 256
static constexpr size_t ST_L0     = ST_BASE + 512;             // 128
static constexpr size_t ST_L1     = ST_BASE + 640;             // 256
static constexpr size_t ST_L2     = ST_BASE + 896;             // 512
static constexpr size_t RMX_GM    = ST_BASE + 1408;            // 512 uint
static constexpr size_t RMN_GM    = ST_BASE + 1920;            // 512 uint
static constexpr size_t RMX_L2    = ST_BASE + 2432;            // 1024 uint
static constexpr size_t RMN_L2    = ST_BASE + 3456;            // 1024 uint
static constexpr int    ST_COUNT  = 4480;

__device__ inline unsigned fmap(float f) {
    unsigned u = __float_as_uint(f);
    return (u & 0x80000000u) ? ~u : (u | 0x80000000u);
}
__device__ inline float funmap(unsigned u) {
    unsigned v = (u & 0x80000000u) ? (u & 0x7fffffffu) : ~u;
    return __uint_as_float(v);
}

// XCD-affinity decode: batch b owns XCD pair {2b,2b+1} (XCD = bid%8 heuristic)
__device__ inline void xcd_decode(int v, int& b, int& t) {
    b = (v & 7) >> 1;
    t = ((v >> 3) << 1) | (v & 1);
}

// ============================================================
// Kernel A: knn (4096) | feat (2048) | L0 layer (256) | init (1)
// ============================================================
__global__ __launch_bounds__(256) void kA(const float* __restrict__ xyz,
                                          const float* __restrict__ pts,
                                          const float* __restrict__ ec_w,
                                          const float* __restrict__ w0,
                                          const float* __restrict__ bias0,
                                          int* __restrict__ edges,
                                          float* __restrict__ afeat,
                                          float* __restrict__ cfeat,
                                          float* __restrict__ l0raw,
                                          float* __restrict__ stL0,
                                          unsigned* __restrict__ stz) {
    __shared__ __align__(16) unsigned char smem[25856];
    int u = blockIdx.x;
    int tid = threadIdx.x;
    if (u < 4096) {
        // ---- wave-cooperative exact KNN (ballot-compaction) ----
        float4* cand = (float4*)smem;
        unsigned long long* bufall = (unsigned long long*)(smem + 16384);
        int b = u >> 10;
        int wave = tid >> 6, lane = tid & 63;
        int n = ((u & 1023) << 2) + wave;
        const float* xb = xyz + (size_t)b * 3 * 4096;
        unsigned long long* wbuf = bufall + wave * 128;

        float xq = xb[n], yq = xb[4096 + n], zq = xb[8192 + n];
        float sqq = __fadd_rn(__fadd_rn(__fmul_rn(xq, xq), __fmul_rn(yq, yq)), __fmul_rn(zq, zq));

        unsigned T = 0xFFFFFFFFu;
        int count = 0;

        auto reduce = [&]() {
            unsigned long long ka = (lane < count) ? wbuf[lane] : ~0ull;
            int ra = 0;
            if (count > 64) {
                unsigned long long kb = (lane + 64 < count) ? wbuf[lane + 64] : ~0ull;
                int rb = 0;
                for (int j = 0; j < count; ++j) {
                    unsigned long long kj = wbuf[j];
                    ra += (kj < ka);
                    rb += (kj < kb);
                }
                if (rb < 25) wbuf[rb] = kb;
            } else {
                for (int j = 0; j < count; ++j) {
                    unsigned long long kj = wbuf[j];
                    ra += (kj < ka);
                }
            }
            if (ra < 25) wbuf[ra] = ka;
            count = 25;
            T = (unsigned)(wbuf[24] >> 32);
        };

        for (int strip = 0; strip < 4; ++strip) {
            __syncthreads();
            for (int i = tid; i < 1024; i += 256) {
                int j = strip * 1024 + i;
                float x = xb[j], y = xb[4096 + j], z = xb[8192 + j];
                float sq = __fadd_rn(__fadd_rn(__fmul_rn(x, x), __fmul_rn(y, y)), __fmul_rn(z, z));
                cand[i] = make_float4(x, y, z, sq);
            }
            __syncthreads();
            for (int t = 0; t < 16; ++t) {
                float4 cv = cand[t * 64 + lane];
                float dot = __fadd_rn(__fadd_rn(__fmul_rn(xq, cv.x), __fmul_rn(yq, cv.y)), __fmul_rn(zq, cv.z));
                float d = __fsub_rn(__fadd_rn(sqq, cv.w), __fmul_rn(2.0f, dot));
                unsigned du = fmap(d);
                bool surv = (du <= T);
                unsigned long long m = __ballot(surv);
                if (m) {
                    if (surv) {
                        int ofs = __popcll(m & ((1ull << lane) - 1ull));
                        unsigned idx = (unsigned)(strip * 1024 + t * 64 + lane);
                        wbuf[count + ofs] = ((unsigned long long)du << 32) | idx;
                    }
                    count += (int)__popcll(m);
                    if (count >= 64) reduce();
                }
            }
        }
        reduce();
        if (lane >= 1 && lane < 25)
            edges[((size_t)(b * 4096 + n)) * KNN + lane - 1] = (int)(unsigned)(wbuf[lane] & 0xFFFFFFFFull);
    } else if (u < 6144) {
        // ---- feat: one 64x32 GEMM slice (a or c) per block ----
        int v = u - 4096;
        int b, t;
        xcd_decode(v, b, t);
        int nchunk = t & 63, sub = t >> 6;
        int which = sub >> 2;
        int o0 = (sub & 3) * 32;
        int n0 = nchunk * 64;

        float* inl = (float*)smem;            // 64*65
        float* wl  = (float*)(smem + 16640);  // 64*36
        const float* pb = pts + (size_t)b * 64 * 4096;

        for (int idx = tid; idx < 64 * 64; idx += 256) {
            int c = idx >> 6, p = idx & 63;
            inl[p * 65 + c] = pb[(size_t)c * 4096 + n0 + p];
        }
        for (int idx = tid; idx < 64 * 32; idx += 256) {
            int cc = idx & 63, o = idx >> 6;
            float w2v = ec_w[(o0 + o) * 128 + 64 + cc];
            wl[cc * 36 + o] = which ? w2v : (ec_w[(o0 + o) * 128 + cc] - w2v);
        }
        __syncthreads();

        int ng = tid & 15, og = tid >> 4;
        float acc[4][2] = {{0.f, 0.f}, {0.f, 0.f}, {0.f, 0.f}, {0.f, 0.f}};
        for (int cc = 0; cc < 64; ++cc) {
            float pv[4];
            #pragma unroll
            for (int r = 0; r < 4; ++r) pv[r] = inl[(ng * 4 + r) * 65 + cc];
            float2 wv = *(const float2*)&wl[cc * 36 + og * 2];
            #pragma unroll
            for (int r = 0; r < 4; ++r) {
                acc[r][0] = fmaf(pv[r], wv.x, acc[r][0]);
                acc[r][1] = fmaf(pv[r], wv.y, acc[r][1]);
            }
        }
        __syncthreads();
        #pragma unroll
        for (int r = 0; r < 4; ++r) {
            wl[(ng * 4 + r) * 36 + og * 2 + 0] = acc[r][0];
            wl[(ng * 4 + r) * 36 + og * 2 + 1] = acc[r][1];
        }
        __syncthreads();
        float* dst = (which ? cfeat : afeat) + ((size_t)(b * 4096 + n0)) * 128 + o0;
        for (int idx = tid; idx < 64 * 32; idx += 256) {
            int p = idx >> 5, o = idx & 31;
            dst[(size_t)p * 128 + o] = wl[p * 36 + o];
        }
    } else if (u < 6400) {
        // ---- L0: concat(xyz,pts)[67] -> 64 outs, 64-pt chunk ----
        int v = u - 6144;
        int b, chunk;
        xcd_decode(v, b, chunk);              // chunk in [0,64)
        int n0 = chunk * 64;
        int q0 = b * 4096 + n0;
        float* inl = (float*)smem;            // [32][68]
        float* wl  = (float*)(smem + 8704);   // [32][68]
        int ng = tid & 15, og = tid >> 4;
        float acc[4][4] = {};

        for (int ct = 0; ct < 67; ct += 32) {
            int CT = (67 - ct < 32) ? (67 - ct) : 32;
            __syncthreads();
            for (int idx = tid; idx < CT * 16; idx += 256) {
                int p4 = idx & 15, c = idx >> 4;
                int ch = ct + c;
                const float* srow = (ch < 3) ? &xyz[((size_t)(b * 3 + ch) << 12) + n0]
                                             : &pts[((size_t)(b * 64 + ch - 3) << 12) + n0];
                float4 v4;
                v4.x = srow[p4 * 4 + 0];
                v4.y = srow[p4 * 4 + 1];
                v4.z = srow[p4 * 4 + 2];
                v4.w = srow[p4 * 4 + 3];
                *(float4*)&inl[c * 68 + p4 * 4] = v4;
            }
            for (int idx = tid; idx < CT * 64; idx += 256) {
                int o = idx & 63, cc = idx >> 6;
                wl[cc * 68 + o] = w0[o * 67 + ct + cc];
            }
            __syncthreads();
            for (int cc = 0; cc < CT; ++cc) {
                float4 pv = *(const float4*)&inl[cc * 68 + ng * 4];
                float4 wv = *(const float4*)&wl[cc * 68 + og * 4];
                float pvv[4] = {pv.x, pv.y, pv.z, pv.w};
                float wvv[4] = {wv.x, wv.y, wv.z, wv.w};
                #pragma unroll
                for (int r = 0; r < 4; ++r)
                    #pragma unroll
                    for (int k = 0; k < 4; ++k)
                        acc[r][k] = fmaf(pvv[r], wvv[k], acc[r][k]);
            }
        }
        #pragma unroll
        for (int k = 0; k < 4; ++k) {
            float bv = bias0[og * 4 + k];
            #pragma unroll
            for (int r = 0; r < 4; ++r) acc[r][k] += bv;
        }
        __syncthreads();
        float* st = inl;  // [64][68]
        #pragma unroll
        for (int r = 0; r < 4; ++r)
            #pragma unroll
            for (int k = 0; k < 4; ++k)
                st[(ng * 4 + r) * 68 + og * 4 + k] = acc[r][k];
        __syncthreads();
        for (int idx = tid; idx < 1024; idx += 256) {
            int p = idx >> 4, o4 = (idx & 15) * 4;
            *(float4*)&l0raw[(size_t)(q0 + p) * 64 + o4] = *(const float4*)&st[p * 68 + o4];
        }
        if (tid < 64) {
            float s1 = 0.f, s2 = 0.f;
            #pragma unroll 8
            for (int p = 0; p < 64; ++p) {
                float vv = st[p * 68 + tid];
                s1 += vv;
                s2 = fmaf(vv, vv, s2);
            }
            atomicAdd(&stL0[tid], s1);
            atomicAdd(&stL0[64 + tid], s2);
        }
    } else {
        // init stats/extremes (skip ST_L0 range [512,640): memset'd + L0 races)
        for (int i = tid; i < ST_COUNT; i += 256) {
            if (i >= 512 && i < 640) continue;
            bool sentinel = (i >= (int)(RMN_GM - ST_BASE) && i < (int)(RMX_L2 - ST_BASE)) ||
                            (i >= (int)(RMN_L2 - ST_BASE));
            stz[i] = sentinel ? 0xFFFFFFFFu : 0u;
        }
    }
}

// ============================================================
// Kernel B: neighbor gather + BN1 stats (1024 blocks)
// ============================================================
__global__ __launch_bounds__(256) void kB(const float* __restrict__ afeat,
                                          const float* __restrict__ cfeat,
                                          const int* __restrict__ edges,
                                          float* __restrict__ M,
                                          float* __restrict__ stBN1) {
    __shared__ __align__(16) unsigned char smem[5824];
    int u = blockIdx.x;
    int tid = threadIdx.x;
    int* eL = (int*)smem;                       // 16*24
    float* red = (float*)(smem + 1536);         // 8*132
    int b, chunk;
    xcd_decode(u, b, chunk);                    // chunk in [0,256)
    int q0 = b * 4096 + chunk * 16;
    for (int idx = tid; idx < 16 * KNN; idx += 256) eL[idx] = edges[(size_t)q0 * KNN + idx];
    __syncthreads();

    int m = tid & 31;
    int g = tid >> 5;
    int bbase = b << 12;
    float s1[4] = {0.f, 0.f, 0.f, 0.f}, s2[4] = {0.f, 0.f, 0.f, 0.f};

    #pragma unroll
    for (int half = 0; half < 2; ++half) {
        int pp = g + half * 8;
        int q = q0 + pp;
        float mx0 = -__builtin_inff(), mx1 = mx0, mx2 = mx0, mx3 = mx0;
        float sv0 = 0.f, sv1 = 0.f, sv2 = 0.f, sv3 = 0.f;
        float qv0 = 0.f, qv1 = 0.f, qv2 = 0.f, qv3 = 0.f;
        #pragma unroll 8
        for (int k = 0; k < KNN; ++k) {
            int e = eL[pp * KNN + k];
            float4 v = *(const float4*)&cfeat[((size_t)(bbase + e) << 7) + m * 4];
            mx0 = fmaxf(mx0, v.x); sv0 += v.x; qv0 = fmaf(v.x, v.x, qv0);
            mx1 = fmaxf(mx1, v.y); sv1 += v.y; qv1 = fmaf(v.y, v.y, qv1);
            mx2 = fmaxf(mx2, v.z); sv2 += v.z; qv2 = fmaf(v.z, v.z, qv2);
            mx3 = fmaxf(mx3, v.w); sv3 += v.w; qv3 = fmaf(v.w, v.w, qv3);
        }
        float4 a = *(const float4*)&afeat[((size_t)q << 7) + m * 4];
        float4 mo = make_float4(a.x + mx0, a.y + mx1, a.z + mx2, a.w + mx3);
        *(float4*)&M[((size_t)q << 7) + m * 4] = mo;
        s1[0] += fmaf(24.f, a.x, sv0); s2[0] += 24.f * a.x * a.x + 2.f * a.x * sv0 + qv0;
        s1[1] += fmaf(24.f, a.y, sv1); s2[1] += 24.f * a.y * a.y + 2.f * a.y * sv1 + qv1;
        s1[2] += fmaf(24.f, a.z, sv2); s2[2] += 24.f * a.z * a.z + 2.f * a.z * sv2 + qv2;
        s1[3] += fmaf(24.f, a.w, sv3); s2[3] += 24.f * a.w * a.w + 2.f * a.w * sv3 + qv3;
    }
    #pragma unroll
    for (int j = 0; j < 4; ++j) red[g * 132 + m * 4 + j] = s1[j];
    __syncthreads();
    if (tid < 128) {
        float t = 0.f;
        #pragma unroll
        for (int gg = 0; gg < 8; ++gg) t += red[gg * 132 + tid];
        atomicAdd(&stBN1[tid], t);
    }
    __syncthreads();
    #pragma unroll
    for (int j = 0; j < 4; ++j) red[g * 132 + m * 4 + j] = s2[j];
    __syncthreads();
    if (tid < 128) {
        float t = 0.f;
        #pragma unroll
        for (int gg = 0; gg < 8; ++gg) t += red[gg * 132 + tid];
        atomicAdd(&stBN1[128 + tid], t);
    }
}

// ============================================================
// 128-pt x 128-out dense layer, 8x8 thread tiles, k-tile 32.
// MODE: 1 = relu(bn(in)), 2 = leaky(bn(in)).
// ============================================================
template<int I, int TO, int MODE, bool RAW, bool MINMAX>
__device__ void layer128(unsigned char* smem, int b, int chunk, int o0,
    const float* __restrict__ inraw, const float* __restrict__ inst, float rcnt,
    const float* __restrict__ ing, const float* __restrict__ inbe,
    const float* __restrict__ W, const float* __restrict__ bias,
    float* __restrict__ outraw, float* __restrict__ outst,
    unsigned* __restrict__ rmax, unsigned* __restrict__ rmin)
{
    float* ns  = (float*)smem;                     // 128
    float* nb  = ns + 128;                         // 128
    float* inl = (float*)(smem + 1024);            // [32][132]
    float* wl  = (float*)(smem + 1024 + 16896);    // [32][132]
    int tid = threadIdx.x;
    int ng = tid & 15, og = tid >> 4;
    int q0 = b * 4096 + chunk * 128;

    if (tid < I) {
        float m = inst[tid] * rcnt;
        float v = inst[I + tid] * rcnt - m * m;
        float sc = ing[tid] / sqrtf(v + 1e-5f);
        ns[tid] = sc;
        nb[tid] = inbe[tid] - m * sc;
    }

    float acc[8][8] = {};
    for (int ct = 0; ct < I; ct += 32) {
        __syncthreads();  // ns ready (iter 0) / prev tile consumed
        const float* src = inraw + (size_t)q0 * I + ct;
        #pragma unroll
        for (int it = 0; it < 4; ++it) {
            int idx = tid + it * 256;
            int c = idx & 31, p4 = idx >> 5;
            float sc_ = ns[ct + c], sh_ = nb[ct + c];
            float4 v;
            v.x = fmaf(src[(size_t)(p4 * 4 + 0) * I + c], sc_, sh_);
            v.y = fmaf(src[(size_t)(p4 * 4 + 1) * I + c], sc_, sh_);
            v.z = fmaf(src[(size_t)(p4 * 4 + 2) * I + c], sc_, sh_);
            v.w = fmaf(src[(size_t)(p4 * 4 + 3) * I + c], sc_, sh_);
            if (MODE == 1) {
                v.x = fmaxf(v.x, 0.f); v.y = fmaxf(v.y, 0.f);
                v.z = fmaxf(v.z, 0.f); v.w = fmaxf(v.w, 0.f);
            } else {
                v.x = (v.x > 0.f) ? v.x : 0.2f * v.x;
                v.y = (v.y > 0.f) ? v.y : 0.2f * v.y;
                v.z = (v.z > 0.f) ? v.z : 0.2f * v.z;
                v.w = (v.w > 0.f) ? v.w : 0.2f * v.w;
            }
            *(float4*)&inl[c * 132 + p4 * 4] = v;
        }
        #pragma unroll
        for (int it = 0; it < 4; ++it) {
            int idx = tid + it * 256;
            int o = idx & 127, c4 = idx >> 7;
            float4 w4 = *(const float4*)&W[(size_t)(o0 + o) * I + ct + c4 * 4];
            wl[(c4 * 4 + 0) * 132 + o] = w4.x;
            wl[(c4 * 4 + 1) * 132 + o] = w4.y;
            wl[(c4 * 4 + 2) * 132 + o] = w4.z;
            wl[(c4 * 4 + 3) * 132 + o] = w4.w;
        }
        __syncthreads();
        for (int cc = 0; cc < 32; ++cc) {
            float4 pl = *(const float4*)&inl[cc * 132 + ng * 4];
            float4 ph = *(const float4*)&inl[cc * 132 + 64 + ng * 4];
            float4 wo = *(const float4*)&wl[cc * 132 + og * 4];
            float4 wh = *(const float4*)&wl[cc * 132 + 64 + og * 4];
            float pv[8] = {pl.x, pl.y, pl.z, pl.w, ph.x, ph.y, ph.z, ph.w};
            float wv[8] = {wo.x, wo.y, wo.z, wo.w, wh.x, wh.y, wh.z, wh.w};
            #pragma unroll
            for (int r = 0; r < 8; ++r)
                #pragma unroll
                for (int k = 0; k < 8; ++k)
                    acc[r][k] = fmaf(pv[r], wv[k], acc[r][k]);
        }
    }

    if (bias != nullptr) {
        #pragma unroll
        for (int k = 0; k < 8; ++k) {
            int o = (k < 4) ? (og * 4 + k) : (64 + og * 4 + k - 4);
            float bv = bias[o0 + o];
            #pragma unroll
            for (int r = 0; r < 8; ++r) acc[r][k] += bv;
        }
    }

    if (RAW) {
        float* st = (float*)(smem + 1024);   // [128][68]
        #pragma unroll
        for (int h = 0; h < 2; ++h) {
            __syncthreads();
            #pragma unroll
            for (int r = 0; r < 8; ++r) {
                int p = (r < 4) ? (ng * 4 + r) : (64 + ng * 4 + r - 4);
                #pragma unroll
                for (int k = 0; k < 4; ++k)
                    st[p * 68 + og * 4 + k] = acc[r][h * 4 + k];
            }
            __syncthreads();
            for (int idx = tid; idx < 2048; idx += 256) {
                int p = idx >> 4, o4 = (idx & 15) * 4;
                *(float4*)&outraw[(size_t)(q0 + p) * TO + h * 64 + o4] = *(const float4*)&st[p * 68 + o4];
            }
            if (tid < 64) {
                float s1 = 0.f, s2 = 0.f;
                #pragma unroll 8
                for (int p = 0; p < 128; ++p) {
                    float vv = st[p * 68 + tid];
                    s1 += vv;
                    s2 = fmaf(vv, vv, s2);
                }
                atomicAdd(&outst[h * 64 + tid], s1);
                atomicAdd(&outst[TO + h * 64 + tid], s2);
            }
        }
    } else {
        float* red = (float*)(smem + 1024);  // [128*17] float4-slots
        __syncthreads();
        #pragma unroll
        for (int k = 0; k < 8; ++k) {
            int o = (k < 4) ? (og * 4 + k) : (64 + og * 4 + k - 4);
            float s1 = 0.f, s2 = 0.f;
            float mx = -__builtin_inff(), mn = __builtin_inff();
            #pragma unroll
            for (int r = 0; r < 8; ++r) {
                float vv = acc[r][k];
                s1 += vv;
                s2 = fmaf(vv, vv, s2);
                mx = fmaxf(mx, vv);
                mn = fminf(mn, vv);
            }
            *(float4*)&red[(o * 17 + ng) * 4] = make_float4(s1, s2, mx, mn);
        }
        __syncthreads();
        if (tid < 128) {
            float s1 = 0.f, s2 = 0.f;
            float mx = -__builtin_inff(), mn = __builtin_inff();
            #pragma unroll
            for (int g2 = 0; g2 < 16; ++g2) {
                float4 t4 = *(const float4*)&red[(tid * 17 + g2) * 4];
                s1 += t4.x;
                s2 += t4.y;
                mx = fmaxf(mx, t4.z);
                mn = fminf(mn, t4.w);
            }
            atomicAdd(&outst[o0 + tid], s1);
            atomicAdd(&outst[TO + o0 + tid], s2);
            if (MINMAX) {
                atomicMax(&rmax[b * TO + o0 + tid], fmap(mx));
                atomicMin(&rmin[b * TO + o0 + tid], fmap(mn));
            }
        }
    }
}

// ============================================================
// Kernel C: GM (128 jobs, minmax) | L1 (128 jobs, raw)
// ============================================================
__global__ __launch_bounds__(256, 4) void kC(const float* __restrict__ M,
                                             const float* __restrict__ stBN1,
                                             const float* __restrict__ ec_g,
                                             const float* __restrict__ ec_b,
                                             const float* __restrict__ gm_w,
                                             float* __restrict__ stGM,
                                             unsigned* __restrict__ rmxGM,
                                             unsigned* __restrict__ rmnGM,
                                             const float* __restrict__ l0raw,
                                             const float* __restrict__ stL0,
                                             const float* __restrict__ g0,
                                             const float* __restrict__ be0,
                                             const float* __restrict__ w1,
                                             const float* __restrict__ bias1,
                                             float* __restrict__ l1raw,
                                             float* __restrict__ stL1) {
    __shared__ __align__(16) unsigned char smem[36864];
    int u = blockIdx.x;
    if (u < 128) {
        int b, chunk;
        xcd_decode(u, b, chunk);   // chunk in [0,32)
        layer128<128, 128, 2, false, true>(smem, b, chunk, 0,
            M, stBN1, 1.0f / 393216.0f, ec_g, ec_b,
            gm_w, nullptr, nullptr, stGM, rmxGM, rmnGM);
    } else {
        int b, chunk;
        xcd_decode(u - 128, b, chunk);
        layer128<64, 128, 1, true, false>(smem, b, chunk, 0,
            l0raw, stL0, 1.0f / 16384.0f, g0, be0,
            w1, bias1, l1raw, stL1, nullptr, nullptr);
    }
}

// ============================================================
// Kernel D: L2 (256 jobs = 128-pt x 128-out halves, minmax)
// ============================================================
__global__ __launch_bounds__(256, 4) void kD(const float* __restrict__ l1raw,
                                             const float* __restrict__ stL1,
                                             const float* __restrict__ g1,
                                             const float* __restrict__ be1,
                                             const float* __restrict__ w2,
                                             const float* __restrict__ bias2,
                                             float* __restrict__ stL2,
                                             unsigned* __restrict__ rmxL2,
                                             unsigned* __restrict__ rmnL2) {
    __shared__ __align__(16) unsigned char smem[36864];
    int u = blockIdx.x;
    int half = u >> 7;
    int b, chunk;
    xcd_decode(u & 127, b, chunk);  // chunk in [0,32)
    layer128<128, 256, 1, false, true>(smem, b, chunk, half * 128,
        l1raw, stL1, 1.0f / 16384.0f, g1, be1,
        w2, bias2, nullptr, stL2, rmxL2, rmnL2);
}

// ============================================================
// Kernel E (1 block): BN consts -> act at raw extremes (exact
// monotone pushthrough) -> fused 384-feature -> final head.
// ============================================================
__global__ __launch_bounds__(256) void kE(const float* __restrict__ stGM,
                                          const float* __restrict__ gm_g,
                                          const float* __restrict__ gm_b,
                                          const unsigned* __restrict__ rmxGM,
                                          const unsigned* __restrict__ rmnGM,
                                          const float* __restrict__ stL2,
                                          const float* __restrict__ g2,
                                          const float* __restrict__ be2,
                                          const unsigned* __restrict__ rmxL2,
                                          const unsigned* __restrict__ rmnL2,
                                          const float* __restrict__ fu_w,
                                          const float* __restrict__ fu_g,
                                          const float* __restrict__ fu_b,
                                          float* __restrict__ out) {
    __shared__ float fl[4 * 384];
    const float rc = 1.0f / 16384.0f;
    int tid = threadIdx.x;
    {   // point branch (relu), O=256
        int o = tid;
        float m = stL2[o] * rc;
        float v = stL2[256 + o] * rc - m * m;
        float sc = g2[o] / sqrtf(v + 1e-5f);
        float sh = be2[o] - m * sc;
        #pragma unroll
        for (int b = 0; b < 4; ++b) {
            float f1 = fmaxf(fmaf(funmap(rmxL2[b * 256 + o]), sc, sh), 0.f);
            float f2 = fmaxf(fmaf(funmap(rmnL2[b * 256 + o]), sc, sh), 0.f);
            fl[b * 384 + o] = fmaxf(f1, f2);
        }
    }
    if (tid < 128) {   // graph branch (leaky), O=128
        int o = tid;
        float m = stGM[o] * rc;
        float v = stGM[128 + o] * rc - m * m;
        float sc = gm_g[o] / sqrtf(v + 1e-5f);
        float sh = gm_b[o] - m * sc;
        #pragma unroll
        for (int b = 0; b < 4; ++b) {
            float x1 = fmaf(funmap(rmxGM[b * 128 + o]), sc, sh);
            x1 = (x1 > 0.f) ? x1 : 0.2f * x1;
            float x2 = fmaf(funmap(rmnGM[b * 128 + o]), sc, sh);
            x2 = (x2 > 0.f) ? x2 : 0.2f * x2;
            fl[b * 384 + 256 + o] = fmaxf(x1, x2);
        }
    }
    __syncthreads();
    int o = tid;
    float f[4];
    #pragma unroll
    for (int bb = 0; bb < 4; ++bb) {
        float acc = 0.f;
        for (int c = 0; c < 384; ++c) acc = fmaf(fl[bb * 384 + c], fu_w[(size_t)o * 384 + c], acc);
        f[bb] = acc;
    }
    float m = 0.25f * (f[0] + f[1] + f[2] + f[3]);
    float var = 0.f;
    #pragma unroll
    for (int bb = 0; bb < 4; ++bb) { float tt = f[bb] - m; var = fmaf(tt, tt, var); }
    var *= 0.25f;
    float inv = 1.0f / sqrtf(var + 1e-5f);
    float gv = fu_g[o], bv = fu_b[o];
    #pragma unroll
    for (int bb = 0; bb < 4; ++bb) {
        float xx = (f[bb] - m) * inv * gv + bv;
        xx = (xx > 0.0f) ? xx : 0.2f * xx;
        out[bb * 256 + o] = xx;
    }
}

extern "C" void kernel_launch(void* const* d_in, const int* in_sizes, int n_in,
                              void* d_out, int out_size, void* d_ws, size_t ws_size,
                              hipStream_t stream) {
    const float* xyz   = (const float*)d_in[0];
    const float* pts   = (const float*)d_in[1];
    const float* ec_w  = (const float*)d_in[2];
    const float* ec_g  = (const float*)d_in[3];
    const float* ec_b  = (const float*)d_in[4];
    const float* gm_w  = (const float*)d_in[5];
    const float* gm_g  = (const float*)d_in[6];
    const float* gm_b  = (const float*)d_in[7];
    const float* w0    = (const float*)d_in[8];
    const float* bias0 = (const float*)d_in[9];
    const float* g0    = (const float*)d_in[10];
    const float* be0   = (const float*)d_in[11];
    const float* w1    = (const float*)d_in[12];
    const float* bias1 = (const float*)d_in[13];
    const float* g1    = (const float*)d_in[14];
    const float* be1   = (const float*)d_in[15];
    const float* w2    = (const float*)d_in[16];
    const float* bias2 = (const float*)d_in[17];
    const float* g2    = (const float*)d_in[18];
    const float* be2   = (const float*)d_in[19];
    const float* fu_w  = (const float*)d_in[20];
    const float* fu_g  = (const float*)d_in[21];
    const float* fu_b  = (const float*)d_in[22];

    float* ws = (float*)d_ws;
    float* out = (float*)d_out;

    // stL0 must be zero before kA's L0 atomics (init block would race)
    hipMemsetAsync(ws + ST_L0, 0, 128 * sizeof(float), stream);

    kA<<<6401, 256, 0, stream>>>(xyz, pts, ec_w, w0, bias0,
                                 (int*)(ws + OFF_EDGES), ws + OFF_A, ws + OFF_C,
                                 ws + OFF_L0, ws + ST_L0, (unsigned*)(ws + ST_BASE));
    kB<<<1024, 256, 0, stream>>>(ws + OFF_A, ws + OFF_C, (int*)(ws + OFF_EDGES),
                                 ws + OFF_M, ws + ST_BN1);
    kC<<<256, 256, 0, stream>>>(ws + OFF_M, ws + ST_BN1, ec_g, ec_b, gm_w,
                                ws + ST_GM, (unsigned*)(ws + RMX_GM), (unsigned*)(ws + RMN_GM),
                                ws + OFF_L0, ws + ST_L0, g0, be0, w1, bias1,
                                ws + OFF_L1, ws + ST_L1);
    kD<<<256, 256, 0, stream>>>(ws + OFF_L1, ws + ST_L1, g1, be1, w2, bias2,
                                ws + ST_L2, (unsigned*)(ws + RMX_L2), (unsigned*)(ws + RMN_L2));
    kE<<<1, 256, 0, stream>>>(ws + ST_GM, gm_g, gm_b,
                              (unsigned*)(ws + RMX_GM), (unsigned*)(ws + RMN_GM),
                              ws + ST_L2, g2, be2,
                              (unsigned*)(ws + RMX_L2), (unsigned*)(ws + RMN_L2),
                              fu_w, fu_g, fu_b, out);
}